// Round 17
// baseline (292.779 us; speedup 1.0000x reference)
//
#include <hip/hip_runtime.h>
#include <hip/hip_bf16.h>

typedef __attribute__((ext_vector_type(8))) _Float16 half8;
typedef __attribute__((ext_vector_type(4))) _Float16 half4;
typedef __attribute__((ext_vector_type(4))) float f32x4;

#define DEVFN __device__ __forceinline__

constexpr int B_ = 4, T_ = 4096, C_ = 1024, H_ = 16, S_ = 256, M_ = 32, D_ = 64;
constexpr int NT_ = B_ * T_;
constexpr float FSCALE = 65536.0f;   // keeps fout out of fp16-subnormal range
constexpr float TWOPI = 6.283185307179586f;

DEVFN half8 cvt8(const float4 a, const float4 b) {
  half8 h;
  h[0] = (_Float16)a.x; h[1] = (_Float16)a.y; h[2] = (_Float16)a.z; h[3] = (_Float16)a.w;
  h[4] = (_Float16)b.x; h[5] = (_Float16)b.y; h[6] = (_Float16)b.z; h[7] = (_Float16)b.w;
  return h;
}

#define GLD16(gsrc, ldst)                                                        \
  __builtin_amdgcn_global_load_lds(                                              \
      (const __attribute__((address_space(1))) uint32_t*)(gsrc),                 \
      (__attribute__((address_space(3))) uint32_t*)(ldst), 16, 0, 0)

// ---------------- diag: ws too small -> encode ws_size into d_out[0] ----------------
__global__ void k_diag(float* __restrict__ out, float wsz) {
  if (threadIdx.x == 0 && blockIdx.x == 0) out[0] = wsz;
}

// ---- k_prep v2: fp16 conversions (Wi, Wo) + Wsh/bsh prep in ONE launch (no x_q pass) ----
__global__ void k_prep(const float* __restrict__ Wi, const float* __restrict__ Wo,
                       const float* __restrict__ Ws, const float* __restrict__ bs,
                       const float* __restrict__ temp,
                       _Float16* __restrict__ Wih, _Float16* __restrict__ Woh,
                       _Float16* __restrict__ Wsh, float* __restrict__ bsh)
{
  const int bid = blockIdx.x;
  const int tid = threadIdx.x;
  if (bid < 512) {                        // Wi -> Wih (1.05M elems)
    const int i = (bid * 256 + tid) * 8;
    float4 a = ((const float4*)(Wi + i))[0];
    float4 b = ((const float4*)(Wi + i))[1];
    *(half8*)(Wih + i) = cvt8(a, b);
  } else if (bid < 1024) {                // Wo -> Woh
    const int i = ((bid - 512) * 256 + tid) * 8;
    float4 a = ((const float4*)(Wo + i))[0];
    float4 b = ((const float4*)(Wo + i))[1];
    *(half8*)(Woh + i) = cvt8(a, b);
  } else {                                // per-head Ws/temp prep (16 blocks)
    const int h = bid - 1024;
    const float invt = 1.0f / temp[h];
    for (int i = tid; i < S_ * D_; i += 256)
      Wsh[(size_t)h * S_ * D_ + i] = (_Float16)(Ws[i] * invt);
    if (tid < S_) bsh[h * S_ + tid] = bs[tid] * invt;
  }
}

// ---- K1 v7: 128x128; A reg-staged from fp32 x_q (cvt8, padded [128][40]);
//   B via GLD16 from Wih (linear). LDS-transposed dual-output epilogue (R15-proven).
__global__ __launch_bounds__(256) void k1_in_proj(
    const float* __restrict__ X, const _Float16* __restrict__ Wih, const float* __restrict__ bi,
    _Float16* __restrict__ tmp_h, _Float16* __restrict__ tmp_hT)
{
  __shared__ _Float16 SMEM[9216];    // As[128][40]@0 (5120), Bs[128*32]@5120 (4096, 16B-aligned); Ep overlays
  _Float16 (*As)[40] = (_Float16 (*)[40])&SMEM[0];
  _Float16* Bs = &SMEM[5120];
  const int tid = threadIdx.x;
  const int orig = blockIdx.y * gridDim.x + blockIdx.x;
  const int wgid = (orig & 7) * 128 + (orig >> 3);
  const int rowBase = (wgid >> 3) * 128;
  const int colBase = (wgid & 7) * 128;
  const int w = tid >> 6, lane = tid & 63;
  const int wr = w >> 1, wc = w & 1;
  const int fr = lane & 15, fg = lane >> 4;
  // A staging coords (reg path)
  const int sr = tid >> 1, sk = (tid & 1) * 16;
  const float* aptr = X + (size_t)(rowBase + sr) * C_ + sk;
  // B staging coords (GLD16 path)
  const int srow0 = w * 16 + (lane >> 2);
  const int srow1 = (4 + w) * 16 + (lane >> 2);
  const int scol  = (lane & 3) * 8;
  const size_t brow0 = (size_t)(colBase + srow0) * C_ + scol;
  const size_t brow1 = (size_t)(colBase + srow1) * C_ + scol;
  f32x4 acc[4][4] = {};
  for (int kt = 0; kt < C_; kt += 32) {
    __syncthreads();
    GLD16(Wih + brow0 + kt, &Bs[w * 512]);
    GLD16(Wih + brow1 + kt, &Bs[(4 + w) * 512]);
    {
      const float* s0 = aptr + kt;
      float4 v0 = ((const float4*)s0)[0], v1 = ((const float4*)s0)[1];
      float4 v2 = ((const float4*)s0)[2], v3 = ((const float4*)s0)[3];
      *(half8*)&As[sr][sk]     = cvt8(v0, v1);
      *(half8*)&As[sr][sk + 8] = cvt8(v2, v3);
    }
    __syncthreads();
    half8 a[4], b[4];
#pragma unroll
    for (int i = 0; i < 4; ++i) a[i] = *(const half8*)&As[wr * 64 + i * 16 + fr][fg * 8];
#pragma unroll
    for (int j = 0; j < 4; ++j) b[j] = *(const half8*)&Bs[(wc * 64 + j * 16 + fr) * 32 + fg * 8];
#pragma unroll
    for (int i = 0; i < 4; ++i)
#pragma unroll
      for (int j = 0; j < 4; ++j)
        acc[i][j] = __builtin_amdgcn_mfma_f32_16x16x32_f16(a[i], b[j], acc[i][j], 0, 0, 0);
  }
  const int bb = rowBase >> 12;
  const int tloc = rowBase & (T_ - 1);
  // tmp_hT: direct half4 stores (proven path)
#pragma unroll
  for (int i = 0; i < 4; ++i) {
#pragma unroll
    for (int j = 0; j < 4; ++j) {
      const int col = colBase + wc * 64 + j * 16 + fr;
      const int hh = col >> 6, d = col & 63;
      const float bv = bi[col];
      const int t0 = tloc + wr * 64 + i * 16 + fg * 4;
      half4 pk;
#pragma unroll
      for (int r = 0; r < 4; ++r) pk[r] = (_Float16)(acc[i][j][r] + bv);
      *(half4*)&tmp_hT[(((size_t)(bb * H_ + hh)) * D_ + d) * T_ + t0] = pk;
    }
  }
  // tmp_h via LDS transpose: two 64-row phases, fully-coalesced half8 stores
  _Float16 (*Ep)[136] = (_Float16 (*)[136])&SMEM[0];
#pragma unroll
  for (int ph = 0; ph < 2; ++ph) {
    __syncthreads();
    if (wr == ph) {
#pragma unroll
      for (int i = 0; i < 4; ++i)
#pragma unroll
        for (int j = 0; j < 4; ++j) {
          const int col = colBase + wc * 64 + j * 16 + fr;
          const float bv = bi[col];
#pragma unroll
          for (int r = 0; r < 4; ++r)
            Ep[i * 16 + fg * 4 + r][wc * 64 + j * 16 + fr] = (_Float16)(acc[i][j][r] + bv);
        }
    }
    __syncthreads();
#pragma unroll
    for (int h2 = 0; h2 < 2; ++h2) {
      const int hh2 = (colBase >> 6) + h2;
      const size_t base = (((size_t)(bb * H_ + hh2)) * T_ + tloc + ph * 64) * D_;
#pragma unroll
      for (int p = 0; p < 2; ++p) {
        const int idx = p * 256 + tid;
        const int trow = idx >> 3, seg = idx & 7;
        *(half8*)(tmp_h + base + (size_t)trow * D_ + seg * 8) =
            *(const half8*)&Ep[trow][h2 * 64 + seg * 8];
      }
    }
  }
}

// ---- K3 v6 (R13-proven): barrier-free + T14 double prefetch. ----
__global__ __launch_bounds__(256) void k3_pool(
    const _Float16* __restrict__ tmp_h, const _Float16* __restrict__ tmp_hT,
    const _Float16* __restrict__ Wsh, const float* __restrict__ bsh,
    float* __restrict__ Zpart, float* __restrict__ colsumP)
{
  __shared__ _Float16 Es[256][72];
  const int tid = threadIdx.x;
  const int kc = blockIdx.x;
  const int bh = blockIdx.y;
  const int hh = bh & (H_ - 1);
  const int w = tid >> 6, lane = tid & 63;
  const int fr = lane & 15, fg = lane >> 4;
  const size_t tmpB  = (size_t)bh * T_ * D_;
  const size_t tmpTB = (size_t)bh * D_ * T_;
  const _Float16* WshH = Wsh + (size_t)hh * S_ * D_;
  float bsreg[4];
#pragma unroll
  for (int nj = 0; nj < 4; ++nj) bsreg[nj] = bsh[hh * S_ + w * 64 + nj * 16 + fr];
  f32x4 acc2[4][4] = {};
  float cacc[4] = {0.f, 0.f, 0.f, 0.f};
  half8 pa[2][4];
  half8 pb[2][4];
  {
    const int t0 = kc * 512;
#pragma unroll
    for (int ks = 0; ks < 2; ++ks)
#pragma unroll
      for (int mi = 0; mi < 4; ++mi)
        pa[ks][mi] = *(const half8*)(tmp_h + tmpB + (size_t)(t0 + mi * 16 + fr) * D_ + ks * 32 + fg * 8);
#pragma unroll
    for (int kt = 0; kt < 2; ++kt)
#pragma unroll
      for (int nj = 0; nj < 4; ++nj)
        pb[kt][nj] = *(const half8*)(tmp_hT + tmpTB + (size_t)(nj * 16 + fr) * T_ + t0 + kt * 32 + fg * 8);
  }
  for (int step = 0; step < 8; ++step) {
    const int t0 = kc * 512 + step * 64;
    const int t1 = t0 + 64;
    f32x4 acc1[4][4] = {};
#pragma unroll
    for (int ks = 0; ks < 2; ++ks) {
      half8 b[4];
#pragma unroll
      for (int nj = 0; nj < 4; ++nj)
        b[nj] = *(const half8*)(WshH + (size_t)(w * 64 + nj * 16 + fr) * D_ + ks * 32 + fg * 8);
#pragma unroll
      for (int mi = 0; mi < 4; ++mi)
#pragma unroll
        for (int nj = 0; nj < 4; ++nj)
          acc1[mi][nj] = __builtin_amdgcn_mfma_f32_16x16x32_f16(pa[ks][mi], b[nj], acc1[mi][nj], 0, 0, 0);
    }
    if (step < 7) {
#pragma unroll
      for (int ks = 0; ks < 2; ++ks)
#pragma unroll
        for (int mi = 0; mi < 4; ++mi)
          pa[ks][mi] = *(const half8*)(tmp_h + tmpB + (size_t)(t1 + mi * 16 + fr) * D_ + ks * 32 + fg * 8);
    }
#pragma unroll
    for (int mi = 0; mi < 4; ++mi) {
#pragma unroll
      for (int nj = 0; nj < 4; ++nj) {
        half4 p;
        float csp = 0.f;
#pragma unroll
        for (int r = 0; r < 4; ++r) {
          const float e = __expf(acc1[mi][nj][r] + bsreg[nj]);
          p[r] = (_Float16)e;
          csp += e;
        }
        cacc[nj] += csp;
        *(half4*)&Es[w * 64 + nj * 16 + fr][mi * 16 + fg * 4] = p;
      }
    }
#pragma unroll
    for (int kt = 0; kt < 2; ++kt) {
      half8 a2[4];
#pragma unroll
      for (int mi = 0; mi < 4; ++mi)
        a2[mi] = *(const half8*)&Es[w * 64 + mi * 16 + fr][kt * 32 + fg * 8];
#pragma unroll
      for (int mi = 0; mi < 4; ++mi)
#pragma unroll
        for (int nj = 0; nj < 4; ++nj)
          acc2[mi][nj] = __builtin_amdgcn_mfma_f32_16x16x32_f16(a2[mi], pb[kt][nj], acc2[mi][nj], 0, 0, 0);
    }
    if (step < 7) {
#pragma unroll
      for (int kt = 0; kt < 2; ++kt)
#pragma unroll
        for (int nj = 0; nj < 4; ++nj)
          pb[kt][nj] = *(const half8*)(tmp_hT + tmpTB + (size_t)(nj * 16 + fr) * T_ + t1 + kt * 32 + fg * 8);
    }
  }
#pragma unroll
  for (int nj = 0; nj < 4; ++nj) {
    float v = cacc[nj];
    v += __shfl_xor(v, 16); v += __shfl_xor(v, 32);
    if (fg == 0) colsumP[((size_t)bh * 8 + kc) * S_ + w * 64 + nj * 16 + fr] = v;
  }
#pragma unroll
  for (int mi = 0; mi < 4; ++mi)
#pragma unroll
    for (int nj = 0; nj < 4; ++nj)
#pragma unroll
      for (int r = 0; r < 4; ++r)
        Zpart[(((size_t)bh * 8 + kc) * S_ + w * 64 + mi * 16 + fg * 4 + r) * D_ + nj * 16 + fr]
            = acc2[mi][nj][r];
}

// ---- K4a: reduce 8 Zpart/colsum partials, normalize, direct DFT (M=32 modes) ----
__global__ __launch_bounds__(256) void k4a_dft(
    const float* __restrict__ Zpart, const float* __restrict__ colsumP,
    float* __restrict__ Fre, float* __restrict__ Fim)
{
  __shared__ float zsh[256][17];
  __shared__ float csh[256];
  __shared__ float tc[256], ts[256];
  const int tid = threadIdx.x;
  const int ic = blockIdx.x;
  const int bh = blockIdx.y;
  {
    const float ang = (float)tid * (TWOPI / 256.0f);
    tc[tid] = cosf(ang); ts[tid] = sinf(ang);
    float c = 0.f;
#pragma unroll
    for (int kc = 0; kc < 8; ++kc) c += colsumP[((size_t)bh * 8 + kc) * S_ + tid];
    csh[tid] = c;
  }
  __syncthreads();
  for (int idx = tid; idx < 256 * 16; idx += 256) {
    const int s = idx >> 4, dd = idx & 15;
    float v = 0.f;
#pragma unroll
    for (int kc = 0; kc < 8; ++kc)
      v += Zpart[(((size_t)bh * 8 + kc) * S_ + s) * D_ + ic * 16 + dd];
    zsh[s][dd] = v / csh[s];
  }
  __syncthreads();
  const int ii = tid >> 4;
  const int mh = tid & 15;
#pragma unroll
  for (int q = 0; q < 2; ++q) {
    const int m = mh + 16 * q;
    float re = 0.f, im = 0.f;
    int k = 0;
    for (int s = 0; s < 256; ++s) {
      const float zv = zsh[s][ii];
      re += zv * tc[k];
      im -= zv * ts[k];
      k = (k + m) & 255;
    }
    Fre[((size_t)bh * D_ + ic * 16 + ii) * M_ + m] = re;
    Fim[((size_t)bh * D_ + ic * 16 + ii) * M_ + m] = im;
  }
}

// ---- K4b: mode-mix + inverse synthesis -> fout_T fp16 (scaled) ----
__global__ __launch_bounds__(256) void k4b_mix(
    const float* __restrict__ Fre, const float* __restrict__ Fim,
    const float* __restrict__ w_re, const float* __restrict__ w_im,
    _Float16* __restrict__ fout_T)
{
  __shared__ _Float16 Fsr[4][64][33];
  __shared__ _Float16 Fsi[4][64][33];
  __shared__ float Gpre[2][4][4][32];
  __shared__ float Gpim[2][4][4][32];
  __shared__ float Gre[4][4][32];
  __shared__ float Gim[4][4][32];
  __shared__ float tc[256], ts[256];
  const int tid = threadIdx.x;
  const int oc = blockIdx.x;
  const int h  = blockIdx.y;
  for (int idx = tid; idx < 4 * 64 * 32; idx += 256) {
    const int b = idx >> 11, rem = idx & 2047, i = rem >> 5, m = rem & 31;
    const size_t off = ((size_t)(b * 16 + h) * D_ + i) * M_ + m;
    Fsr[b][i][m] = (_Float16)Fre[off];
    Fsi[b][i][m] = (_Float16)Fim[off];
  }
  {
    const float ang = (float)tid * (TWOPI / 256.0f);
    tc[tid] = cosf(ang); ts[tid] = sinf(ang);
  }
  __syncthreads();
  {
    const int ih = tid >> 7, o = (tid >> 5) & 3, m = tid & 31;
    float gre[4] = {0,0,0,0}, gim[4] = {0,0,0,0};
    for (int i = ih * 32; i < ih * 32 + 32; ++i) {
      const size_t wo = (((size_t)h * D_ + i) * D_ + oc * 4 + o) * M_ + m;
      const float wre = w_re[wo], wim = w_im[wo];
#pragma unroll
      for (int b = 0; b < 4; ++b) {
        const float fre = (float)Fsr[b][i][m], fim = (float)Fsi[b][i][m];
        gre[b] += fre * wre - fim * wim;
        gim[b] += fre * wim + fim * wre;
      }
    }
#pragma unroll
    for (int b = 0; b < 4; ++b) { Gpre[ih][b][o][m] = gre[b]; Gpim[ih][b][o][m] = gim[b]; }
  }
  __syncthreads();
  for (int idx = tid; idx < 512; idx += 256) {
    const int b = idx >> 7, o = (idx >> 5) & 3, m = idx & 31;
    Gre[b][o][m] = Gpre[0][b][o][m] + Gpre[1][b][o][m];
    Gim[b][o][m] = Gpim[0][b][o][m] + Gpim[1][b][o][m];
  }
  __syncthreads();
  {
    const int b = tid >> 6, o = (tid >> 4) & 3, sc = tid & 15;
    for (int s5 = 0; s5 < 16; ++s5) {
      const int s = sc * 16 + s5;
      float v = Gre[b][o][0];
      int km = s;
#pragma unroll
      for (int m = 1; m < 32; ++m) {
        v += 2.0f * (Gre[b][o][m] * tc[km] - Gim[b][o][m] * ts[km]);
        km = (km + s) & 255;
      }
      fout_T[((size_t)(b * 16 + h) * D_ + oc * 4 + o) * S_ + s] = (_Float16)(v * (FSCALE / 256.0f));
    }
  }
}

// ---- K5 v7 (R13-proven): fused scatter with in-register rowsum ----
__global__ __launch_bounds__(256) void k5_scatter(
    const _Float16* __restrict__ Wsh, const float* __restrict__ bsh,
    const _Float16* __restrict__ fout_T, _Float16* __restrict__ tmp_io)
{
  __shared__ _Float16 Fs[64][264];
  __shared__ _Float16 Es[64][264];
  __shared__ float bshl[256];
  const int tid = threadIdx.x;
  const int orig = blockIdx.y * gridDim.x + blockIdx.x;
  const int nidx = (orig & 7) * 64 + (orig >> 3);
  const int bh = nidx >> 3;
  const int tcn = nidx & 7;
  const int hh = bh & (H_ - 1);
  const int w = tid >> 6, lane = tid & 63;
  const int fr = lane & 15, fg = lane >> 4;
  {
    const int row = tid >> 2, c0 = (tid & 3) * 64;
    const _Float16* src = fout_T + (size_t)bh * D_ * S_ + (size_t)row * S_ + c0;
#pragma unroll
    for (int q = 0; q < 8; ++q)
      *(half8*)&Fs[row][c0 + q * 8] = ((const half8*)src)[q];
  }
  bshl[tid] = bsh[hh * S_ + tid];
  __syncthreads();
  const _Float16* WshH = Wsh + (size_t)hh * S_ * D_;
  const size_t tmpB = (size_t)bh * T_ * D_ + (size_t)tcn * 512 * D_;
  const int trow = w * 16 + fr;
  half8 bf0, bf1;
  {
    const _Float16* p = tmp_io + tmpB + (size_t)trow * D_ + fg * 8;
    bf0 = *(const half8*)p;
    bf1 = *(const half8*)(p + 32);
  }
  for (int step = 0; step < 8; ++step) {
    float sumE = 0.f;
    {
      f32x4 acc1[8];
#pragma unroll
      for (int mi = 0; mi < 8; ++mi) acc1[mi] = (f32x4){0.f, 0.f, 0.f, 0.f};
#pragma unroll
      for (int mi = 0; mi < 8; ++mi) {
        const half8 a0 = *(const half8*)(WshH + (size_t)(mi * 16 + fr) * D_ + fg * 8);
        acc1[mi] = __builtin_amdgcn_mfma_f32_16x16x32_f16(a0, bf0, acc1[mi], 0, 0, 0);
      }
#pragma unroll
      for (int mi = 0; mi < 8; ++mi) {
        const half8 a1 = *(const half8*)(WshH + (size_t)(mi * 16 + fr) * D_ + 32 + fg * 8);
        acc1[mi] = __builtin_amdgcn_mfma_f32_16x16x32_f16(a1, bf1, acc1[mi], 0, 0, 0);
      }
#pragma unroll
      for (int mi = 0; mi < 8; ++mi) {
        const float4 bv = *(const float4*)&bshl[mi * 16 + fg * 4];
        float e0 = __expf(acc1[mi][0] + bv.x);
        float e1 = __expf(acc1[mi][1] + bv.y);
        float e2 = __expf(acc1[mi][2] + bv.z);
        float e3 = __expf(acc1[mi][3] + bv.w);
        sumE += (e0 + e1) + (e2 + e3);
        half4 pk;
        pk[0] = (_Float16)e0; pk[1] = (_Float16)e1;
        pk[2] = (_Float16)e2; pk[3] = (_Float16)e3;
        *(half4*)&Es[trow][mi * 16 + fg * 4] = pk;
      }
    }
    {
      f32x4 acc1[8];
#pragma unroll
      for (int mi = 0; mi < 8; ++mi) acc1[mi] = (f32x4){0.f, 0.f, 0.f, 0.f};
#pragma unroll
      for (int mi = 0; mi < 8; ++mi) {
        const half8 a0 = *(const half8*)(WshH + (size_t)((8 + mi) * 16 + fr) * D_ + fg * 8);
        acc1[mi] = __builtin_amdgcn_mfma_f32_16x16x32_f16(a0, bf0, acc1[mi], 0, 0, 0);
      }
#pragma unroll
      for (int mi = 0; mi < 8; ++mi) {
        const half8 a1 = *(const half8*)(WshH + (size_t)((8 + mi) * 16 + fr) * D_ + 32 + fg * 8);
        acc1[mi] = __builtin_amdgcn_mfma_f32_16x16x32_f16(a1, bf1, acc1[mi], 0, 0, 0);
      }
#pragma unroll
      for (int mi = 0; mi < 8; ++mi) {
        const float4 bv = *(const float4*)&bshl[(8 + mi) * 16 + fg * 4];
        float e0 = __expf(acc1[mi][0] + bv.x);
        float e1 = __expf(acc1[mi][1] + bv.y);
        float e2 = __expf(acc1[mi][2] + bv.z);
        float e3 = __expf(acc1[mi][3] + bv.w);
        sumE += (e0 + e1) + (e2 + e3);
        half4 pk;
        pk[0] = (_Float16)e0; pk[1] = (_Float16)e1;
        pk[2] = (_Float16)e2; pk[3] = (_Float16)e3;
        *(half4*)&Es[trow][(8 + mi) * 16 + fg * 4] = pk;
      }
    }
    sumE += __shfl_xor(sumE, 16);
    sumE += __shfl_xor(sumE, 32);
    if (step < 7) {
      const _Float16* p = tmp_io + tmpB + (size_t)((step + 1) * 64 + trow) * D_ + fg * 8;
      bf0 = *(const half8*)p;
      bf1 = *(const half8*)(p + 32);
    }
    f32x4 acc2[4];
#pragma unroll
    for (int nj = 0; nj < 4; ++nj) acc2[nj] = (f32x4){0.f, 0.f, 0.f, 0.f};
#pragma unroll
    for (int ks = 0; ks < 8; ++ks) {
      const half8 ea = *(const half8*)&Es[w * 16 + fr][ks * 32 + fg * 8];
#pragma unroll
      for (int nj = 0; nj < 4; ++nj) {
        const half8 fb = *(const half8*)&Fs[nj * 16 + fr][ks * 32 + fg * 8];
        acc2[nj] = __builtin_amdgcn_mfma_f32_16x16x32_f16(ea, fb, acc2[nj], 0, 0, 0);
      }
    }
    const int tstep0 = tcn * 512 + step * 64;
    {
      float ri[4];
#pragma unroll
      for (int r = 0; r < 4; ++r) ri[r] = 1.0f / __shfl(sumE, fg * 4 + r);
#pragma unroll
      for (int r = 0; r < 4; ++r)
#pragma unroll
        for (int nj = 0; nj < 4; ++nj)
          Es[w * 16 + fg * 4 + r][nj * 16 + fr] = (_Float16)(acc2[nj][r] * ri[r]);
      const int trow8 = lane >> 3, seg = lane & 7;
#pragma unroll
      for (int p = 0; p < 2; ++p) {
        const int rloc = w * 16 + p * 8 + trow8;
        *(half8*)(tmp_io + (size_t)bh * T_ * D_ + (size_t)(tstep0 + rloc) * D_ + seg * 8) =
            *(const half8*)&Es[rloc][seg * 8];
      }
    }
  }
}

// ---- K6 v2 (R15-proven m97-style): Y = out_tok @ Wo^T * (1/FSCALE) + bo. ----
__global__ __launch_bounds__(256) void k6_out_proj(
    const _Float16* __restrict__ OT, const _Float16* __restrict__ Woh, const float* __restrict__ bo,
    float* __restrict__ Y)
{
  __shared__ _Float16 As[128 * 32];
  __shared__ _Float16 Bs[128 * 32];
  const int tid = threadIdx.x;
  const int orig = blockIdx.y * gridDim.x + blockIdx.x;
  const int wgid = (orig & 7) * 128 + (orig >> 3);
  const int rowBase = (wgid >> 3) * 128;
  const int colBase = (wgid & 7) * 128;
  const int w = tid >> 6, lane = tid & 63;
  const int wr = w >> 1, wc = w & 1;
  const int fr = lane & 15, fg = lane >> 4;
  const int srow0 = w * 16 + (lane >> 2);
  const int srow1 = (4 + w) * 16 + (lane >> 2);
  const int scol  = (lane & 3) * 8;
  const int g0 = rowBase + srow0, g1 = rowBase + srow1;
  const int bb = g0 >> 12;
  const int t0 = g0 & (T_ - 1), t1 = g1 & (T_ - 1);
  const size_t brow0 = (size_t)(colBase + srow0) * C_ + scol;
  const size_t brow1 = (size_t)(colBase + srow1) * C_ + scol;
  f32x4 acc[4][4] = {};
  for (int kt = 0; kt < C_; kt += 32) {
    const int c0 = kt + scol;
    const int hh0 = c0 >> 6, d0 = c0 & 63;
    __syncthreads();
    GLD16(OT + (((size_t)(bb * H_ + hh0)) * T_ + t0) * D_ + d0, &As[w * 512]);
    GLD16(OT + (((size_t)(bb * H_ + hh0)) * T_ + t1) * D_ + d0, &As[(4 + w) * 512]);
    GLD16(Woh + brow0 + kt, &Bs[w * 512]);
    GLD16(Woh + brow1 + kt, &Bs[(4 + w) * 512]);
    __syncthreads();
    half8 a[4], b[4];
#pragma unroll
    for (int i = 0; i < 4; ++i) a[i] = *(const half8*)&As[(wr * 64 + i * 16 + fr) * 32 + fg * 8];
#pragma unroll
    for (int j = 0; j < 4; ++j) b[j] = *(const half8*)&Bs[(wc * 64 + j * 16 + fr) * 32 + fg * 8];
#pragma unroll
    for (int i = 0; i < 4; ++i)
#pragma unroll
      for (int j = 0; j < 4; ++j)
        acc[i][j] = __builtin_amdgcn_mfma_f32_16x16x32_f16(a[i], b[j], acc[i][j], 0, 0, 0);
  }
#pragma unroll
  for (int i = 0; i < 4; ++i) {
#pragma unroll
    for (int j = 0; j < 4; ++j) {
      const int col = colBase + wc * 64 + j * 16 + fr;
      const float bv = bo[col];
      const int g0o = rowBase + wr * 64 + i * 16 + fg * 4;
#pragma unroll
      for (int r = 0; r < 4; ++r)
        Y[(size_t)(g0o + r) * C_ + col] = acc[i][j][r] * (1.0f / FSCALE) + bv;
    }
  }
}

extern "C" void kernel_launch(void* const* d_in, const int* in_sizes, int n_in,
                              void* d_out, int out_size, void* d_ws, size_t ws_size,
                              hipStream_t stream)
{
  const float* x_q  = (const float*)d_in[0];
  const float* Wi   = (const float*)d_in[3];
  const float* bi   = (const float*)d_in[4];
  const float* Ws   = (const float*)d_in[5];
  const float* bs   = (const float*)d_in[6];
  const float* temp = (const float*)d_in[7];
  const float* w_re = (const float*)d_in[8];
  const float* w_im = (const float*)d_in[9];
  const float* Wo   = (const float*)d_in[10];
  const float* bo   = (const float*)d_in[11];
  float* Y = (float*)d_out;

  char* ws = (char*)d_ws;
  size_t off = 0;
  auto alloc = [&](size_t bytes) { size_t o = off; off += (bytes + 255) & ~(size_t)255; return o; };
  const size_t o_tmp  = alloc((size_t)NT_ * C_ * 2);
  const size_t o_Wsh  = alloc((size_t)H_ * S_ * D_ * 2);
  const size_t o_bsh  = alloc((size_t)H_ * S_ * 4);
  const size_t o_Zp   = alloc((size_t)B_ * H_ * 8 * S_ * D_ * 4);
  const size_t o_colP = alloc((size_t)B_ * H_ * 8 * S_ * 4);
  const size_t o_Fre  = alloc((size_t)B_ * H_ * D_ * M_ * 4);
  const size_t o_Fim  = alloc((size_t)B_ * H_ * D_ * M_ * 4);
  const size_t o_fout = alloc((size_t)B_ * H_ * D_ * S_ * 2);
  const size_t o_Wih  = alloc((size_t)C_ * C_ * 2);
  const size_t o_Woh  = alloc((size_t)C_ * C_ * 2);
  if (off > ws_size) {
    k_diag<<<1, 64, 0, stream>>>(Y, (float)ws_size);
    return;
  }

  _Float16* tmp    = (_Float16*)(ws + o_tmp);
  _Float16* Wsh    = (_Float16*)(ws + o_Wsh);
  float*    bsh    = (float*)(ws + o_bsh);
  float*    Zpart  = (float*)(ws + o_Zp);
  float*    colsumP= (float*)(ws + o_colP);
  float*    Fre    = (float*)(ws + o_Fre);
  float*    Fim    = (float*)(ws + o_Fim);
  _Float16* fout_T = (_Float16*)(ws + o_fout);
  _Float16* Wih    = (_Float16*)(ws + o_Wih);
  _Float16* Woh    = (_Float16*)(ws + o_Woh);
  // d_out (64 MB fp32) is dead until k6: second half holds tmp_hT.
  _Float16* tmp_hT = (_Float16*)((char*)d_out + (size_t)NT_ * C_ * 2);

  k_prep    <<<dim3(1040),    256, 0, stream>>>(Wi, Wo, Ws, bs, temp, Wih, Woh, Wsh, bsh);
  k1_in_proj<<<dim3(8, 128),  256, 0, stream>>>(x_q, Wih, bi, tmp, tmp_hT);
  k3_pool   <<<dim3(8, B_*H_), 256, 0, stream>>>(tmp, tmp_hT, Wsh, bsh, Zpart, colsumP);
  k4a_dft   <<<dim3(4, B_*H_), 256, 0, stream>>>(Zpart, colsumP, Fre, Fim);
  k4b_mix   <<<dim3(16, H_),   256, 0, stream>>>(Fre, Fim, w_re, w_im, fout_T);
  k5_scatter<<<dim3(8, B_*H_), 256, 0, stream>>>(Wsh, bsh, fout_T, tmp);
  k6_out_proj<<<dim3(8, 128),  256, 0, stream>>>(tmp, Woh, bo, Y);
}

// Round 18
// 279.313 us; speedup vs baseline: 1.0482x; 1.0482x over previous
//
#include <hip/hip_runtime.h>
#include <hip/hip_bf16.h>

typedef __attribute__((ext_vector_type(8))) _Float16 half8;
typedef __attribute__((ext_vector_type(4))) _Float16 half4;
typedef __attribute__((ext_vector_type(4))) float f32x4;

#define DEVFN __device__ __forceinline__

constexpr int B_ = 4, T_ = 4096, C_ = 1024, H_ = 16, S_ = 256, M_ = 32, D_ = 64;
constexpr int NT_ = B_ * T_;
constexpr float FSCALE = 65536.0f;   // keeps fout out of fp16-subnormal range
constexpr float TWOPI = 6.283185307179586f;

DEVFN half8 cvt8(const float4 a, const float4 b) {
  half8 h;
  h[0] = (_Float16)a.x; h[1] = (_Float16)a.y; h[2] = (_Float16)a.z; h[3] = (_Float16)a.w;
  h[4] = (_Float16)b.x; h[5] = (_Float16)b.y; h[6] = (_Float16)b.z; h[7] = (_Float16)b.w;
  return h;
}

#define GLD16(gsrc, ldst)                                                        \
  __builtin_amdgcn_global_load_lds(                                              \
      (const __attribute__((address_space(1))) uint32_t*)(gsrc),                 \
      (__attribute__((address_space(3))) uint32_t*)(ldst), 16, 0, 0)

// ---------------- diag: ws too small -> encode ws_size into d_out[0] ----------------
__global__ void k_diag(float* __restrict__ out, float wsz) {
  if (threadIdx.x == 0 && blockIdx.x == 0) out[0] = wsz;
}

// ---- k_prep: merged fp16 conversions (x_q, Wi, Wo) + Wsh/bsh prep in ONE launch ----
__global__ void k_prep(const float* __restrict__ xq, const float* __restrict__ Wi,
                       const float* __restrict__ Wo, const float* __restrict__ Ws,
                       const float* __restrict__ bs, const float* __restrict__ temp,
                       _Float16* __restrict__ Xh, _Float16* __restrict__ Wih,
                       _Float16* __restrict__ Woh, _Float16* __restrict__ Wsh,
                       float* __restrict__ bsh)
{
  const int bid = blockIdx.x;
  const int tid = threadIdx.x;
  if (bid < 8192) {                       // x_q -> Xh (16.78M elems)
    const int i = (bid * 256 + tid) * 8;
    float4 a = ((const float4*)(xq + i))[0];
    float4 b = ((const float4*)(xq + i))[1];
    *(half8*)(Xh + i) = cvt8(a, b);
  } else if (bid < 8704) {                // Wi -> Wih (1.05M elems)
    const int i = ((bid - 8192) * 256 + tid) * 8;
    float4 a = ((const float4*)(Wi + i))[0];
    float4 b = ((const float4*)(Wi + i))[1];
    *(half8*)(Wih + i) = cvt8(a, b);
  } else if (bid < 9216) {                // Wo -> Woh
    const int i = ((bid - 8704) * 256 + tid) * 8;
    float4 a = ((const float4*)(Wo + i))[0];
    float4 b = ((const float4*)(Wo + i))[1];
    *(half8*)(Woh + i) = cvt8(a, b);
  } else {                                // per-head Ws/temp prep (16 blocks)
    const int h = bid - 9216;
    const float invt = 1.0f / temp[h];
    for (int i = tid; i < S_ * D_; i += 256)
      Wsh[(size_t)h * S_ * D_ + i] = (_Float16)(Ws[i] * invt);
    if (tid < S_) bsh[h * S_ + tid] = bs[tid] * invt;
  }
}

// ---- K1 v4 (R13/R15-proven): m97-style 128x128 + LDS-transposed epilogue.
__global__ __launch_bounds__(256) void k1_in_proj(
    const _Float16* __restrict__ Xh, const _Float16* __restrict__ Wih, const float* __restrict__ bi,
    _Float16* __restrict__ tmp_h, _Float16* __restrict__ tmp_hT)
{
  __shared__ _Float16 SMEM[8704];    // 17.4 KB: As(8KB)+Bs(8KB) during K-loop; Ep[64][136] after
  _Float16* As = SMEM;
  _Float16* Bs = SMEM + 4096;
  const int tid = threadIdx.x;
  const int orig = blockIdx.y * gridDim.x + blockIdx.x;
  const int wgid = (orig & 7) * 128 + (orig >> 3);
  const int rowBase = (wgid >> 3) * 128;
  const int colBase = (wgid & 7) * 128;
  const int w = tid >> 6, lane = tid & 63;
  const int wr = w >> 1, wc = w & 1;
  const int fr = lane & 15, fg = lane >> 4;
  const int srow0 = w * 16 + (lane >> 2);
  const int srow1 = (4 + w) * 16 + (lane >> 2);
  const int scol  = (lane & 3) * 8;
  const size_t arow0 = (size_t)(rowBase + srow0) * C_ + scol;
  const size_t arow1 = (size_t)(rowBase + srow1) * C_ + scol;
  const size_t brow0 = (size_t)(colBase + srow0) * C_ + scol;
  const size_t brow1 = (size_t)(colBase + srow1) * C_ + scol;
  f32x4 acc[4][4] = {};
  for (int kt = 0; kt < C_; kt += 32) {
    __syncthreads();
    GLD16(Xh  + arow0 + kt, &As[w * 512]);
    GLD16(Xh  + arow1 + kt, &As[(4 + w) * 512]);
    GLD16(Wih + brow0 + kt, &Bs[w * 512]);
    GLD16(Wih + brow1 + kt, &Bs[(4 + w) * 512]);
    __syncthreads();
    half8 a[4], b[4];
#pragma unroll
    for (int i = 0; i < 4; ++i) a[i] = *(const half8*)&As[(wr * 64 + i * 16 + fr) * 32 + fg * 8];
#pragma unroll
    for (int j = 0; j < 4; ++j) b[j] = *(const half8*)&Bs[(wc * 64 + j * 16 + fr) * 32 + fg * 8];
#pragma unroll
    for (int i = 0; i < 4; ++i)
#pragma unroll
      for (int j = 0; j < 4; ++j)
        acc[i][j] = __builtin_amdgcn_mfma_f32_16x16x32_f16(a[i], b[j], acc[i][j], 0, 0, 0);
  }
  const int bb = rowBase >> 12;
  const int tloc = rowBase & (T_ - 1);
  // tmp_hT: direct half4 stores (proven path)
#pragma unroll
  for (int i = 0; i < 4; ++i) {
#pragma unroll
    for (int j = 0; j < 4; ++j) {
      const int col = colBase + wc * 64 + j * 16 + fr;
      const int hh = col >> 6, d = col & 63;
      const float bv = bi[col];
      const int t0 = tloc + wr * 64 + i * 16 + fg * 4;
      half4 pk;
#pragma unroll
      for (int r = 0; r < 4; ++r) pk[r] = (_Float16)(acc[i][j][r] + bv);
      *(half4*)&tmp_hT[(((size_t)(bb * H_ + hh)) * D_ + d) * T_ + t0] = pk;
    }
  }
  // tmp_h via LDS transpose: two 64-row phases, fully-coalesced half8 stores
  _Float16 (*Ep)[136] = (_Float16 (*)[136])&SMEM[0];
#pragma unroll
  for (int ph = 0; ph < 2; ++ph) {
    __syncthreads();
    if (wr == ph) {
#pragma unroll
      for (int i = 0; i < 4; ++i)
#pragma unroll
        for (int j = 0; j < 4; ++j) {
          const int col = colBase + wc * 64 + j * 16 + fr;
          const float bv = bi[col];
#pragma unroll
          for (int r = 0; r < 4; ++r)
            Ep[i * 16 + fg * 4 + r][wc * 64 + j * 16 + fr] = (_Float16)(acc[i][j][r] + bv);
        }
    }
    __syncthreads();
#pragma unroll
    for (int h2 = 0; h2 < 2; ++h2) {
      const int hh2 = (colBase >> 6) + h2;
      const size_t base = (((size_t)(bb * H_ + hh2)) * T_ + tloc + ph * 64) * D_;
#pragma unroll
      for (int p = 0; p < 2; ++p) {
        const int idx = p * 256 + tid;
        const int trow = idx >> 3, seg = idx & 7;
        *(half8*)(tmp_h + base + (size_t)trow * D_ + seg * 8) =
            *(const half8*)&Ep[trow][h2 * 64 + seg * 8];
      }
    }
  }
}

// ---- K3 v6 (R13-proven): barrier-free + T14 double prefetch. ----
__global__ __launch_bounds__(256) void k3_pool(
    const _Float16* __restrict__ tmp_h, const _Float16* __restrict__ tmp_hT,
    const _Float16* __restrict__ Wsh, const float* __restrict__ bsh,
    float* __restrict__ Zpart, float* __restrict__ colsumP)
{
  __shared__ _Float16 Es[256][72];
  const int tid = threadIdx.x;
  const int kc = blockIdx.x;
  const int bh = blockIdx.y;
  const int hh = bh & (H_ - 1);
  const int w = tid >> 6, lane = tid & 63;
  const int fr = lane & 15, fg = lane >> 4;
  const size_t tmpB  = (size_t)bh * T_ * D_;
  const size_t tmpTB = (size_t)bh * D_ * T_;
  const _Float16* WshH = Wsh + (size_t)hh * S_ * D_;
  float bsreg[4];
#pragma unroll
  for (int nj = 0; nj < 4; ++nj) bsreg[nj] = bsh[hh * S_ + w * 64 + nj * 16 + fr];
  f32x4 acc2[4][4] = {};
  float cacc[4] = {0.f, 0.f, 0.f, 0.f};
  half8 pa[2][4];
  half8 pb[2][4];
  {
    const int t0 = kc * 512;
#pragma unroll
    for (int ks = 0; ks < 2; ++ks)
#pragma unroll
      for (int mi = 0; mi < 4; ++mi)
        pa[ks][mi] = *(const half8*)(tmp_h + tmpB + (size_t)(t0 + mi * 16 + fr) * D_ + ks * 32 + fg * 8);
#pragma unroll
    for (int kt = 0; kt < 2; ++kt)
#pragma unroll
      for (int nj = 0; nj < 4; ++nj)
        pb[kt][nj] = *(const half8*)(tmp_hT + tmpTB + (size_t)(nj * 16 + fr) * T_ + t0 + kt * 32 + fg * 8);
  }
  for (int step = 0; step < 8; ++step) {
    const int t0 = kc * 512 + step * 64;
    const int t1 = t0 + 64;
    f32x4 acc1[4][4] = {};
#pragma unroll
    for (int ks = 0; ks < 2; ++ks) {
      half8 b[4];
#pragma unroll
      for (int nj = 0; nj < 4; ++nj)
        b[nj] = *(const half8*)(WshH + (size_t)(w * 64 + nj * 16 + fr) * D_ + ks * 32 + fg * 8);
#pragma unroll
      for (int mi = 0; mi < 4; ++mi)
#pragma unroll
        for (int nj = 0; nj < 4; ++nj)
          acc1[mi][nj] = __builtin_amdgcn_mfma_f32_16x16x32_f16(pa[ks][mi], b[nj], acc1[mi][nj], 0, 0, 0);
    }
    if (step < 7) {
#pragma unroll
      for (int ks = 0; ks < 2; ++ks)
#pragma unroll
        for (int mi = 0; mi < 4; ++mi)
          pa[ks][mi] = *(const half8*)(tmp_h + tmpB + (size_t)(t1 + mi * 16 + fr) * D_ + ks * 32 + fg * 8);
    }
#pragma unroll
    for (int mi = 0; mi < 4; ++mi) {
#pragma unroll
      for (int nj = 0; nj < 4; ++nj) {
        half4 p;
        float csp = 0.f;
#pragma unroll
        for (int r = 0; r < 4; ++r) {
          const float e = __expf(acc1[mi][nj][r] + bsreg[nj]);
          p[r] = (_Float16)e;
          csp += e;
        }
        cacc[nj] += csp;
        *(half4*)&Es[w * 64 + nj * 16 + fr][mi * 16 + fg * 4] = p;
      }
    }
#pragma unroll
    for (int kt = 0; kt < 2; ++kt) {
      half8 a2[4];
#pragma unroll
      for (int mi = 0; mi < 4; ++mi)
        a2[mi] = *(const half8*)&Es[w * 64 + mi * 16 + fr][kt * 32 + fg * 8];
#pragma unroll
      for (int mi = 0; mi < 4; ++mi)
#pragma unroll
        for (int nj = 0; nj < 4; ++nj)
          acc2[mi][nj] = __builtin_amdgcn_mfma_f32_16x16x32_f16(a2[mi], pb[kt][nj], acc2[mi][nj], 0, 0, 0);
    }
    if (step < 7) {
#pragma unroll
      for (int kt = 0; kt < 2; ++kt)
#pragma unroll
        for (int nj = 0; nj < 4; ++nj)
          pb[kt][nj] = *(const half8*)(tmp_hT + tmpTB + (size_t)(nj * 16 + fr) * T_ + t1 + kt * 32 + fg * 8);
    }
  }
#pragma unroll
  for (int nj = 0; nj < 4; ++nj) {
    float v = cacc[nj];
    v += __shfl_xor(v, 16); v += __shfl_xor(v, 32);
    if (fg == 0) colsumP[((size_t)bh * 8 + kc) * S_ + w * 64 + nj * 16 + fr] = v;
  }
#pragma unroll
  for (int mi = 0; mi < 4; ++mi)
#pragma unroll
    for (int nj = 0; nj < 4; ++nj)
#pragma unroll
      for (int r = 0; r < 4; ++r)
        Zpart[(((size_t)bh * 8 + kc) * S_ + w * 64 + mi * 16 + fg * 4 + r) * D_ + nj * 16 + fr]
            = acc2[mi][nj][r];
}

// ---- K4a: reduce 8 Zpart/colsum partials, normalize, direct DFT (M=32 modes) ----
__global__ __launch_bounds__(256) void k4a_dft(
    const float* __restrict__ Zpart, const float* __restrict__ colsumP,
    float* __restrict__ Fre, float* __restrict__ Fim)
{
  __shared__ float zsh[256][17];
  __shared__ float csh[256];
  __shared__ float tc[256], ts[256];
  const int tid = threadIdx.x;
  const int ic = blockIdx.x;
  const int bh = blockIdx.y;
  {
    const float ang = (float)tid * (TWOPI / 256.0f);
    tc[tid] = cosf(ang); ts[tid] = sinf(ang);
    float c = 0.f;
#pragma unroll
    for (int kc = 0; kc < 8; ++kc) c += colsumP[((size_t)bh * 8 + kc) * S_ + tid];
    csh[tid] = c;
  }
  __syncthreads();
  for (int idx = tid; idx < 256 * 16; idx += 256) {
    const int s = idx >> 4, dd = idx & 15;
    float v = 0.f;
#pragma unroll
    for (int kc = 0; kc < 8; ++kc)
      v += Zpart[(((size_t)bh * 8 + kc) * S_ + s) * D_ + ic * 16 + dd];
    zsh[s][dd] = v / csh[s];
  }
  __syncthreads();
  const int ii = tid >> 4;
  const int mh = tid & 15;
#pragma unroll
  for (int q = 0; q < 2; ++q) {
    const int m = mh + 16 * q;
    float re = 0.f, im = 0.f;
    int k = 0;
    for (int s = 0; s < 256; ++s) {
      const float zv = zsh[s][ii];
      re += zv * tc[k];
      im -= zv * ts[k];
      k = (k + m) & 255;
    }
    Fre[((size_t)bh * D_ + ic * 16 + ii) * M_ + m] = re;
    Fim[((size_t)bh * D_ + ic * 16 + ii) * M_ + m] = im;
  }
}

// ---- K4b: mode-mix + inverse synthesis -> fout_T fp16 (scaled) ----
__global__ __launch_bounds__(256) void k4b_mix(
    const float* __restrict__ Fre, const float* __restrict__ Fim,
    const float* __restrict__ w_re, const float* __restrict__ w_im,
    _Float16* __restrict__ fout_T)
{
  __shared__ _Float16 Fsr[4][64][33];
  __shared__ _Float16 Fsi[4][64][33];
  __shared__ float Gpre[2][4][4][32];
  __shared__ float Gpim[2][4][4][32];
  __shared__ float Gre[4][4][32];
  __shared__ float Gim[4][4][32];
  __shared__ float tc[256], ts[256];
  const int tid = threadIdx.x;
  const int oc = blockIdx.x;
  const int h  = blockIdx.y;
  for (int idx = tid; idx < 4 * 64 * 32; idx += 256) {
    const int b = idx >> 11, rem = idx & 2047, i = rem >> 5, m = rem & 31;
    const size_t off = ((size_t)(b * 16 + h) * D_ + i) * M_ + m;
    Fsr[b][i][m] = (_Float16)Fre[off];
    Fsi[b][i][m] = (_Float16)Fim[off];
  }
  {
    const float ang = (float)tid * (TWOPI / 256.0f);
    tc[tid] = cosf(ang); ts[tid] = sinf(ang);
  }
  __syncthreads();
  {
    const int ih = tid >> 7, o = (tid >> 5) & 3, m = tid & 31;
    float gre[4] = {0,0,0,0}, gim[4] = {0,0,0,0};
    for (int i = ih * 32; i < ih * 32 + 32; ++i) {
      const size_t wo = (((size_t)h * D_ + i) * D_ + oc * 4 + o) * M_ + m;
      const float wre = w_re[wo], wim = w_im[wo];
#pragma unroll
      for (int b = 0; b < 4; ++b) {
        const float fre = (float)Fsr[b][i][m], fim = (float)Fsi[b][i][m];
        gre[b] += fre * wre - fim * wim;
        gim[b] += fre * wim + fim * wre;
      }
    }
#pragma unroll
    for (int b = 0; b < 4; ++b) { Gpre[ih][b][o][m] = gre[b]; Gpim[ih][b][o][m] = gim[b]; }
  }
  __syncthreads();
  for (int idx = tid; idx < 512; idx += 256) {
    const int b = idx >> 7, o = (idx >> 5) & 3, m = idx & 31;
    Gre[b][o][m] = Gpre[0][b][o][m] + Gpre[1][b][o][m];
    Gim[b][o][m] = Gpim[0][b][o][m] + Gpim[1][b][o][m];
  }
  __syncthreads();
  {
    const int b = tid >> 6, o = (tid >> 4) & 3, sc = tid & 15;
    for (int s5 = 0; s5 < 16; ++s5) {
      const int s = sc * 16 + s5;
      float v = Gre[b][o][0];
      int km = s;
#pragma unroll
      for (int m = 1; m < 32; ++m) {
        v += 2.0f * (Gre[b][o][m] * tc[km] - Gim[b][o][m] * ts[km]);
        km = (km + s) & 255;
      }
      fout_T[((size_t)(b * 16 + h) * D_ + oc * 4 + o) * S_ + s] = (_Float16)(v * (FSCALE / 256.0f));
    }
  }
}

// ---- K5 v7 (R13-proven): fused scatter with in-register rowsum ----
__global__ __launch_bounds__(256) void k5_scatter(
    const _Float16* __restrict__ Wsh, const float* __restrict__ bsh,
    const _Float16* __restrict__ fout_T, _Float16* __restrict__ tmp_io)
{
  __shared__ _Float16 Fs[64][264];
  __shared__ _Float16 Es[64][264];
  __shared__ float bshl[256];
  const int tid = threadIdx.x;
  const int orig = blockIdx.y * gridDim.x + blockIdx.x;
  const int nidx = (orig & 7) * 64 + (orig >> 3);
  const int bh = nidx >> 3;
  const int tcn = nidx & 7;
  const int hh = bh & (H_ - 1);
  const int w = tid >> 6, lane = tid & 63;
  const int fr = lane & 15, fg = lane >> 4;
  {
    const int row = tid >> 2, c0 = (tid & 3) * 64;
    const _Float16* src = fout_T + (size_t)bh * D_ * S_ + (size_t)row * S_ + c0;
#pragma unroll
    for (int q = 0; q < 8; ++q)
      *(half8*)&Fs[row][c0 + q * 8] = ((const half8*)src)[q];
  }
  bshl[tid] = bsh[hh * S_ + tid];
  __syncthreads();
  const _Float16* WshH = Wsh + (size_t)hh * S_ * D_;
  const size_t tmpB = (size_t)bh * T_ * D_ + (size_t)tcn * 512 * D_;
  const int trow = w * 16 + fr;
  half8 bf0, bf1;
  {
    const _Float16* p = tmp_io + tmpB + (size_t)trow * D_ + fg * 8;
    bf0 = *(const half8*)p;
    bf1 = *(const half8*)(p + 32);
  }
  for (int step = 0; step < 8; ++step) {
    float sumE = 0.f;
    {
      f32x4 acc1[8];
#pragma unroll
      for (int mi = 0; mi < 8; ++mi) acc1[mi] = (f32x4){0.f, 0.f, 0.f, 0.f};
#pragma unroll
      for (int mi = 0; mi < 8; ++mi) {
        const half8 a0 = *(const half8*)(WshH + (size_t)(mi * 16 + fr) * D_ + fg * 8);
        acc1[mi] = __builtin_amdgcn_mfma_f32_16x16x32_f16(a0, bf0, acc1[mi], 0, 0, 0);
      }
#pragma unroll
      for (int mi = 0; mi < 8; ++mi) {
        const half8 a1 = *(const half8*)(WshH + (size_t)(mi * 16 + fr) * D_ + 32 + fg * 8);
        acc1[mi] = __builtin_amdgcn_mfma_f32_16x16x32_f16(a1, bf1, acc1[mi], 0, 0, 0);
      }
#pragma unroll
      for (int mi = 0; mi < 8; ++mi) {
        const float4 bv = *(const float4*)&bshl[mi * 16 + fg * 4];
        float e0 = __expf(acc1[mi][0] + bv.x);
        float e1 = __expf(acc1[mi][1] + bv.y);
        float e2 = __expf(acc1[mi][2] + bv.z);
        float e3 = __expf(acc1[mi][3] + bv.w);
        sumE += (e0 + e1) + (e2 + e3);
        half4 pk;
        pk[0] = (_Float16)e0; pk[1] = (_Float16)e1;
        pk[2] = (_Float16)e2; pk[3] = (_Float16)e3;
        *(half4*)&Es[trow][mi * 16 + fg * 4] = pk;
      }
    }
    {
      f32x4 acc1[8];
#pragma unroll
      for (int mi = 0; mi < 8; ++mi) acc1[mi] = (f32x4){0.f, 0.f, 0.f, 0.f};
#pragma unroll
      for (int mi = 0; mi < 8; ++mi) {
        const half8 a0 = *(const half8*)(WshH + (size_t)((8 + mi) * 16 + fr) * D_ + fg * 8);
        acc1[mi] = __builtin_amdgcn_mfma_f32_16x16x32_f16(a0, bf0, acc1[mi], 0, 0, 0);
      }
#pragma unroll
      for (int mi = 0; mi < 8; ++mi) {
        const half8 a1 = *(const half8*)(WshH + (size_t)((8 + mi) * 16 + fr) * D_ + 32 + fg * 8);
        acc1[mi] = __builtin_amdgcn_mfma_f32_16x16x32_f16(a1, bf1, acc1[mi], 0, 0, 0);
      }
#pragma unroll
      for (int mi = 0; mi < 8; ++mi) {
        const float4 bv = *(const float4*)&bshl[(8 + mi) * 16 + fg * 4];
        float e0 = __expf(acc1[mi][0] + bv.x);
        float e1 = __expf(acc1[mi][1] + bv.y);
        float e2 = __expf(acc1[mi][2] + bv.z);
        float e3 = __expf(acc1[mi][3] + bv.w);
        sumE += (e0 + e1) + (e2 + e3);
        half4 pk;
        pk[0] = (_Float16)e0; pk[1] = (_Float16)e1;
        pk[2] = (_Float16)e2; pk[3] = (_Float16)e3;
        *(half4*)&Es[trow][(8 + mi) * 16 + fg * 4] = pk;
      }
    }
    sumE += __shfl_xor(sumE, 16);
    sumE += __shfl_xor(sumE, 32);
    if (step < 7) {
      const _Float16* p = tmp_io + tmpB + (size_t)((step + 1) * 64 + trow) * D_ + fg * 8;
      bf0 = *(const half8*)p;
      bf1 = *(const half8*)(p + 32);
    }
    f32x4 acc2[4];
#pragma unroll
    for (int nj = 0; nj < 4; ++nj) acc2[nj] = (f32x4){0.f, 0.f, 0.f, 0.f};
#pragma unroll
    for (int ks = 0; ks < 8; ++ks) {
      const half8 ea = *(const half8*)&Es[w * 16 + fr][ks * 32 + fg * 8];
#pragma unroll
      for (int nj = 0; nj < 4; ++nj) {
        const half8 fb = *(const half8*)&Fs[nj * 16 + fr][ks * 32 + fg * 8];
        acc2[nj] = __builtin_amdgcn_mfma_f32_16x16x32_f16(ea, fb, acc2[nj], 0, 0, 0);
      }
    }
    const int tstep0 = tcn * 512 + step * 64;
    {
      float ri[4];
#pragma unroll
      for (int r = 0; r < 4; ++r) ri[r] = 1.0f / __shfl(sumE, fg * 4 + r);
#pragma unroll
      for (int r = 0; r < 4; ++r)
#pragma unroll
        for (int nj = 0; nj < 4; ++nj)
          Es[w * 16 + fg * 4 + r][nj * 16 + fr] = (_Float16)(acc2[nj][r] * ri[r]);
      const int trow8 = lane >> 3, seg = lane & 7;
#pragma unroll
      for (int p = 0; p < 2; ++p) {
        const int rloc = w * 16 + p * 8 + trow8;
        *(half8*)(tmp_io + (size_t)bh * T_ * D_ + (size_t)(tstep0 + rloc) * D_ + seg * 8) =
            *(const half8*)&Es[rloc][seg * 8];
      }
    }
  }
}

// ---- K6 v2 (R15-proven m97-style): Y = out_tok @ Wo^T * (1/FSCALE) + bo. ----
__global__ __launch_bounds__(256) void k6_out_proj(
    const _Float16* __restrict__ OT, const _Float16* __restrict__ Woh, const float* __restrict__ bo,
    float* __restrict__ Y)
{
  __shared__ _Float16 As[128 * 32];
  __shared__ _Float16 Bs[128 * 32];
  const int tid = threadIdx.x;
  const int orig = blockIdx.y * gridDim.x + blockIdx.x;
  const int wgid = (orig & 7) * 128 + (orig >> 3);
  const int rowBase = (wgid >> 3) * 128;
  const int colBase = (wgid & 7) * 128;
  const int w = tid >> 6, lane = tid & 63;
  const int wr = w >> 1, wc = w & 1;
  const int fr = lane & 15, fg = lane >> 4;
  const int srow0 = w * 16 + (lane >> 2);
  const int srow1 = (4 + w) * 16 + (lane >> 2);
  const int scol  = (lane & 3) * 8;
  const int g0 = rowBase + srow0, g1 = rowBase + srow1;
  const int bb = g0 >> 12;
  const int t0 = g0 & (T_ - 1), t1 = g1 & (T_ - 1);
  const size_t brow0 = (size_t)(colBase + srow0) * C_ + scol;
  const size_t brow1 = (size_t)(colBase + srow1) * C_ + scol;
  f32x4 acc[4][4] = {};
  for (int kt = 0; kt < C_; kt += 32) {
    const int c0 = kt + scol;
    const int hh0 = c0 >> 6, d0 = c0 & 63;
    __syncthreads();
    GLD16(OT + (((size_t)(bb * H_ + hh0)) * T_ + t0) * D_ + d0, &As[w * 512]);
    GLD16(OT + (((size_t)(bb * H_ + hh0)) * T_ + t1) * D_ + d0, &As[(4 + w) * 512]);
    GLD16(Woh + brow0 + kt, &Bs[w * 512]);
    GLD16(Woh + brow1 + kt, &Bs[(4 + w) * 512]);
    __syncthreads();
    half8 a[4], b[4];
#pragma unroll
    for (int i = 0; i < 4; ++i) a[i] = *(const half8*)&As[(wr * 64 + i * 16 + fr) * 32 + fg * 8];
#pragma unroll
    for (int j = 0; j < 4; ++j) b[j] = *(const half8*)&Bs[(wc * 64 + j * 16 + fr) * 32 + fg * 8];
#pragma unroll
    for (int i = 0; i < 4; ++i)
#pragma unroll
      for (int j = 0; j < 4; ++j)
        acc[i][j] = __builtin_amdgcn_mfma_f32_16x16x32_f16(a[i], b[j], acc[i][j], 0, 0, 0);
  }
#pragma unroll
  for (int i = 0; i < 4; ++i) {
#pragma unroll
    for (int j = 0; j < 4; ++j) {
      const int col = colBase + wc * 64 + j * 16 + fr;
      const float bv = bo[col];
      const int g0o = rowBase + wr * 64 + i * 16 + fg * 4;
#pragma unroll
      for (int r = 0; r < 4; ++r)
        Y[(size_t)(g0o + r) * C_ + col] = acc[i][j][r] * (1.0f / FSCALE) + bv;
    }
  }
}

extern "C" void kernel_launch(void* const* d_in, const int* in_sizes, int n_in,
                              void* d_out, int out_size, void* d_ws, size_t ws_size,
                              hipStream_t stream)
{
  const float* x_q  = (const float*)d_in[0];
  const float* Wi   = (const float*)d_in[3];
  const float* bi   = (const float*)d_in[4];
  const float* Ws   = (const float*)d_in[5];
  const float* bs   = (const float*)d_in[6];
  const float* temp = (const float*)d_in[7];
  const float* w_re = (const float*)d_in[8];
  const float* w_im = (const float*)d_in[9];
  const float* Wo   = (const float*)d_in[10];
  const float* bo   = (const float*)d_in[11];
  float* Y = (float*)d_out;

  char* ws = (char*)d_ws;
  size_t off = 0;
  auto alloc = [&](size_t bytes) { size_t o = off; off += (bytes + 255) & ~(size_t)255; return o; };
  const size_t o_tmp  = alloc((size_t)NT_ * C_ * 2);
  const size_t o_Wsh  = alloc((size_t)H_ * S_ * D_ * 2);
  const size_t o_bsh  = alloc((size_t)H_ * S_ * 4);
  const size_t o_Zp   = alloc((size_t)B_ * H_ * 8 * S_ * D_ * 4);
  const size_t o_colP = alloc((size_t)B_ * H_ * 8 * S_ * 4);
  const size_t o_Fre  = alloc((size_t)B_ * H_ * D_ * M_ * 4);
  const size_t o_Fim  = alloc((size_t)B_ * H_ * D_ * M_ * 4);
  const size_t o_fout = alloc((size_t)B_ * H_ * D_ * S_ * 2);
  const size_t o_Wih  = alloc((size_t)C_ * C_ * 2);
  const size_t o_Woh  = alloc((size_t)C_ * C_ * 2);
  if (off > ws_size) {
    k_diag<<<1, 64, 0, stream>>>(Y, (float)ws_size);
    return;
  }

  _Float16* tmp    = (_Float16*)(ws + o_tmp);
  _Float16* Wsh    = (_Float16*)(ws + o_Wsh);
  float*    bsh    = (float*)(ws + o_bsh);
  float*    Zpart  = (float*)(ws + o_Zp);
  float*    colsumP= (float*)(ws + o_colP);
  float*    Fre    = (float*)(ws + o_Fre);
  float*    Fim    = (float*)(ws + o_Fim);
  _Float16* fout_T = (_Float16*)(ws + o_fout);
  _Float16* Wih    = (_Float16*)(ws + o_Wih);
  _Float16* Woh    = (_Float16*)(ws + o_Woh);
  // d_out (64 MB fp32) is dead until k6: first half holds Xh, second half tmp_hT.
  _Float16* Xh     = (_Float16*)d_out;
  _Float16* tmp_hT = (_Float16*)((char*)d_out + (size_t)NT_ * C_ * 2);

  k_prep    <<<dim3(9232),    256, 0, stream>>>(x_q, Wi, Wo, Ws, bs, temp, Xh, Wih, Woh, Wsh, bsh);
  k1_in_proj<<<dim3(8, 128),  256, 0, stream>>>(Xh, Wih, bi, tmp, tmp_hT);
  k3_pool   <<<dim3(8, B_*H_), 256, 0, stream>>>(tmp, tmp_hT, Wsh, bsh, Zpart, colsumP);
  k4a_dft   <<<dim3(4, B_*H_), 256, 0, stream>>>(Zpart, colsumP, Fre, Fim);
  k4b_mix   <<<dim3(16, H_),   256, 0, stream>>>(Fre, Fim, w_re, w_im, fout_T);
  k5_scatter<<<dim3(8, B_*H_), 256, 0, stream>>>(Wsh, bsh, fout_T, tmp);
  k6_out_proj<<<dim3(8, 128),  256, 0, stream>>>(tmp, Woh, bo, Y);
}